// Round 9
// baseline (1125.278 us; speedup 1.0000x reference)
//
#include <hip/hip_runtime.h>
#include <hip/hip_fp16.h>

#define NN 100000
#define NE 3200000
#define NG 128
#define BN_EPS 1e-5f

#define NBUK 782          // ceil(100000 / 128)
#define BSHIFT 7          // bucket = dst >> 7 (128 nodes per bucket)
#define BCAP 6144         // slab capacity per bucket (mean 4096, +32 sigma)

#define GRID_MB 512       // 2 blocks/CU guaranteed co-resident (manual grid barrier)
#define NTHR 512
#define PBMAX 2048        // partial-buffer column stride

typedef _Float16 h2v __attribute__((ext_vector_type(2)));

struct Params {
    const float* x; const int* src; const int* dst; const int* batch;
    const float* w1l; const float* b1; const float* w1r; const float* bn1g; const float* bn1b;
    const float* w2l; const float* b2; const float* w2r; const float* bn2g; const float* bn2b;
    const float* w3l; const float* b3; const float* w3r; const float* bn3g; const float* bn3b;
    const float* fc1w; const float* fc1b; const float* fc2w; const float* fc2b;
    float* out;
    int* csr_src; float* hB; __half* hH;
    unsigned int* slab; int* slab_cursor; int* bucket_base; int* row_ptr; float* deg_inv;
    float* part; float* sbv; int* bar;
};

// shared-memory overlays (union via char buffer; max = BK at 28,928 B)
struct SmemBK {
    int lds_csr[BCAP];
    int sdeg[128]; int sscan[128]; int slcur[128];
    float swl[256]; float swr[256]; float sb1[64];
    float ssum[64]; float ssq[64];
};
struct SmemSage {
    h2v wl2s[32][68]; h2v wr2s[32][68];
    h2v tAh[32][36]; h2v tXh[32][36];
    float ssum[64]; float ssq[64];
};

// ---------- manual grid barrier: one dedicated slot per sync point ----------
// slots zeroed via hipMemsetAsync before launch (re-poison-safe).
// Co-residency guaranteed by grid=512 @ __launch_bounds__(512,4).
__device__ inline void gsync(int* bar, int slot) {
    __syncthreads();
    if (threadIdx.x == 0) {
        __hip_atomic_fetch_add(&bar[slot], 1, __ATOMIC_ACQ_REL, __HIP_MEMORY_SCOPE_AGENT);
        while (__hip_atomic_load(&bar[slot], __ATOMIC_ACQUIRE, __HIP_MEMORY_SCOPE_AGENT) < GRID_MB) {
            __builtin_amdgcn_s_sleep(2);
        }
    }
    __syncthreads();
}

// ---------- device helpers ----------

__device__ inline void reduce_sb_phase(const Params& p, char* smem,
                                       const float* gamma, const float* beta) {
    int tid = threadIdx.x, bid = blockIdx.x;
    if (bid >= 64) return;
    float* rs = (float*)smem;
    float* rq = rs + NTHR;
    int c = bid;
    float sv = 0.f, qv = 0.f;
    for (int b = tid; b < GRID_MB; b += NTHR) {
        sv += p.part[(2 * c) * PBMAX + b];
        qv += p.part[(2 * c + 1) * PBMAX + b];
    }
    rs[tid] = sv; rq[tid] = qv;
    __syncthreads();
    for (int off = NTHR / 2; off > 0; off >>= 1) {
        if (tid < off) { rs[tid] += rs[tid + off]; rq[tid] += rq[tid + off]; }
        __syncthreads();
    }
    if (tid == 0) {
        float m = rs[0] / (float)NN;
        float var = rq[0] / (float)NN - m * m;
        float sc = gamma[c] * rsqrtf(var + BN_EPS);
        p.sbv[c] = sc;
        p.sbv[64 + c] = beta[c] - m * sc;
    }
}

__device__ inline void bnrelu_phase(const Params& p, char* smem) {
    int tid = threadIdx.x, bid = blockIdx.x;
    float* ssc = (float*)smem;
    float* sbi = ssc + 64;
    if (tid < 64) { ssc[tid] = p.sbv[tid]; sbi[tid] = p.sbv[64 + tid]; }
    __syncthreads();
    int total = NN * 16;
    for (int i = bid * NTHR + tid; i < total; i += GRID_MB * NTHR) {
        float4 v = ((const float4*)p.hB)[i];
        int c4 = (i & 15) * 4;
        v.x = fmaxf(v.x * ssc[c4 + 0] + sbi[c4 + 0], 0.f);
        v.y = fmaxf(v.y * ssc[c4 + 1] + sbi[c4 + 1], 0.f);
        v.z = fmaxf(v.z * ssc[c4 + 2] + sbi[c4 + 2], 0.f);
        v.w = fmaxf(v.w * ssc[c4 + 3] + sbi[c4 + 3], 0.f);
        __half2 p0 = __floats2half2_rn(v.x, v.y);
        __half2 p1 = __floats2half2_rn(v.z, v.w);
        uint2 o;
        o.x = *(unsigned int*)&p0;
        o.y = *(unsigned int*)&p1;
        ((uint2*)p.hH)[i] = o;
    }
}

__device__ inline void sage_phase(const Params& p, char* smem,
                                  const float* wl, const float* bl, const float* wr) {
    SmemSage* s = (SmemSage*)smem;
    int tid = threadIdx.x, bid = blockIdx.x;
    for (int idx = tid; idx < 2048; idx += NTHR) {
        int j = idx & 63, kk = idx >> 6;
        float2 l = ((const float2*)wl)[j * 32 + kk];
        float2 r = ((const float2*)wr)[j * 32 + kk];
        s->wl2s[kk][j] = h2v{(_Float16)l.x, (_Float16)l.y};
        s->wr2s[kk][j] = h2v{(_Float16)r.x, (_Float16)r.y};
    }
    if (tid < 64) { s->ssum[tid] = 0.f; s->ssq[tid] = 0.f; }
    __syncthreads();

    int g = tid & 15, ni = tid >> 4;
    const uint2* tbl = (const uint2*)p.hH;
    const int ntiles = NN / 32;   // 3125

    for (int tile = bid; tile < ntiles; tile += GRID_MB) {
        int n = tile * 32 + ni;
        float ax = 0.f, ay = 0.f, az = 0.f, aw = 0.f;
        int r0 = p.row_ptr[n], r1 = p.row_ptr[n + 1];
        int e = r0;
        for (; e + 8 <= r1; e += 8) {
            int s0 = p.csr_src[e],     s1 = p.csr_src[e + 1], s2 = p.csr_src[e + 2], s3 = p.csr_src[e + 3];
            int s4 = p.csr_src[e + 4], s5 = p.csr_src[e + 5], s6 = p.csr_src[e + 6], s7 = p.csr_src[e + 7];
            uint2 v0 = tbl[(size_t)s0 * 16 + g];
            uint2 v1 = tbl[(size_t)s1 * 16 + g];
            uint2 v2 = tbl[(size_t)s2 * 16 + g];
            uint2 v3 = tbl[(size_t)s3 * 16 + g];
            uint2 v4 = tbl[(size_t)s4 * 16 + g];
            uint2 v5 = tbl[(size_t)s5 * 16 + g];
            uint2 v6 = tbl[(size_t)s6 * 16 + g];
            uint2 v7 = tbl[(size_t)s7 * 16 + g];
            float2 f;
            f = __half22float2(*(__half2*)&v0.x); ax += f.x; ay += f.y;
            f = __half22float2(*(__half2*)&v0.y); az += f.x; aw += f.y;
            f = __half22float2(*(__half2*)&v1.x); ax += f.x; ay += f.y;
            f = __half22float2(*(__half2*)&v1.y); az += f.x; aw += f.y;
            f = __half22float2(*(__half2*)&v2.x); ax += f.x; ay += f.y;
            f = __half22float2(*(__half2*)&v2.y); az += f.x; aw += f.y;
            f = __half22float2(*(__half2*)&v3.x); ax += f.x; ay += f.y;
            f = __half22float2(*(__half2*)&v3.y); az += f.x; aw += f.y;
            f = __half22float2(*(__half2*)&v4.x); ax += f.x; ay += f.y;
            f = __half22float2(*(__half2*)&v4.y); az += f.x; aw += f.y;
            f = __half22float2(*(__half2*)&v5.x); ax += f.x; ay += f.y;
            f = __half22float2(*(__half2*)&v5.y); az += f.x; aw += f.y;
            f = __half22float2(*(__half2*)&v6.x); ax += f.x; ay += f.y;
            f = __half22float2(*(__half2*)&v6.y); az += f.x; aw += f.y;
            f = __half22float2(*(__half2*)&v7.x); ax += f.x; ay += f.y;
            f = __half22float2(*(__half2*)&v7.y); az += f.x; aw += f.y;
        }
        for (; e < r1; ++e) {
            int sx = p.csr_src[e];
            uint2 v = tbl[(size_t)sx * 16 + g];
            float2 f;
            f = __half22float2(*(__half2*)&v.x); ax += f.x; ay += f.y;
            f = __half22float2(*(__half2*)&v.y); az += f.x; aw += f.y;
        }
        float di = p.deg_inv[n];
        uint2 rsv = tbl[(size_t)n * 16 + g];
        ax *= di; ay *= di; az *= di; aw *= di;
        s->tAh[ni][2 * g]     = h2v{(_Float16)ax, (_Float16)ay};
        s->tAh[ni][2 * g + 1] = h2v{(_Float16)az, (_Float16)aw};
        *(uint2*)&s->tXh[ni][2 * g] = rsv;
        __syncthreads();

        float4 o = ((const float4*)bl)[g];
#pragma unroll 4
        for (int kk = 0; kk < 32; kk++) {
            h2v a2 = s->tAh[ni][kk];
            h2v x2 = s->tXh[ni][kk];
            h2v l0 = s->wl2s[kk][4 * g + 0], l1 = s->wl2s[kk][4 * g + 1];
            h2v l2 = s->wl2s[kk][4 * g + 2], l3 = s->wl2s[kk][4 * g + 3];
            h2v r0v = s->wr2s[kk][4 * g + 0], r1v = s->wr2s[kk][4 * g + 1];
            h2v r2v = s->wr2s[kk][4 * g + 2], r3v = s->wr2s[kk][4 * g + 3];
#if __has_builtin(__builtin_amdgcn_fdot2)
            o.x = __builtin_amdgcn_fdot2(a2, l0, o.x, false);
            o.y = __builtin_amdgcn_fdot2(a2, l1, o.y, false);
            o.z = __builtin_amdgcn_fdot2(a2, l2, o.z, false);
            o.w = __builtin_amdgcn_fdot2(a2, l3, o.w, false);
            o.x = __builtin_amdgcn_fdot2(x2, r0v, o.x, false);
            o.y = __builtin_amdgcn_fdot2(x2, r1v, o.y, false);
            o.z = __builtin_amdgcn_fdot2(x2, r2v, o.z, false);
            o.w = __builtin_amdgcn_fdot2(x2, r3v, o.w, false);
#else
            float b0 = (float)a2.x, b1 = (float)a2.y, x0 = (float)x2.x, x1 = (float)x2.y;
            o.x += b0 * (float)l0.x + b1 * (float)l0.y + x0 * (float)r0v.x + x1 * (float)r0v.y;
            o.y += b0 * (float)l1.x + b1 * (float)l1.y + x0 * (float)r1v.x + x1 * (float)r1v.y;
            o.z += b0 * (float)l2.x + b1 * (float)l2.y + x0 * (float)r2v.x + x1 * (float)r2v.y;
            o.w += b0 * (float)l3.x + b1 * (float)l3.y + x0 * (float)r3v.x + x1 * (float)r3v.y;
#endif
        }
        ((float4*)p.hB)[(size_t)n * 16 + g] = o;

        float4 qv = make_float4(o.x * o.x, o.y * o.y, o.z * o.z, o.w * o.w);
#pragma unroll
        for (int m = 16; m <= 32; m <<= 1) {
            o.x += __shfl_xor(o.x, m); o.y += __shfl_xor(o.y, m);
            o.z += __shfl_xor(o.z, m); o.w += __shfl_xor(o.w, m);
            qv.x += __shfl_xor(qv.x, m); qv.y += __shfl_xor(qv.y, m);
            qv.z += __shfl_xor(qv.z, m); qv.w += __shfl_xor(qv.w, m);
        }
        if ((tid & 48) == 0) {
            atomicAdd(&s->ssum[4 * g + 0], o.x); atomicAdd(&s->ssum[4 * g + 1], o.y);
            atomicAdd(&s->ssum[4 * g + 2], o.z); atomicAdd(&s->ssum[4 * g + 3], o.w);
            atomicAdd(&s->ssq[4 * g + 0], qv.x);  atomicAdd(&s->ssq[4 * g + 1], qv.y);
            atomicAdd(&s->ssq[4 * g + 2], qv.z);  atomicAdd(&s->ssq[4 * g + 3], qv.w);
        }
        __syncthreads();
    }
    if (tid < 64) {
        p.part[(2 * tid) * PBMAX + bid]     = s->ssum[tid];
        p.part[(2 * tid + 1) * PBMAX + bid] = s->ssq[tid];
    }
}

// ---------- the mega kernel ----------

__global__ void __launch_bounds__(NTHR, 4) k_mega(Params p) {
    int tid = threadIdx.x, bid = blockIdx.x;
    __shared__ __align__(16) char smem[28928];
    int slot = 0;

    // ---- P0: zero slab cursors ----
    {
        int gi = bid * NTHR + tid;
        if (gi < NBUK) p.slab_cursor[gi] = 0;
    }
    gsync(p.bar, slot++);

    // ---- P1: bucketed edge scatter ----
    {
        int* hist  = (int*)smem;            // NBUK
        int* cbase = hist + NBUK;           // NBUK
        const int EPB = (NE + GRID_MB - 1) / GRID_MB;   // 6250
        int eBeg = bid * EPB;
        int eEnd = min(eBeg + EPB, NE);
        for (int t = tid; t < NBUK; t += NTHR) hist[t] = 0;
        __syncthreads();
        for (int e = eBeg + tid; e < eEnd; e += NTHR)
            atomicAdd(&hist[p.dst[e] >> BSHIFT], 1);
        __syncthreads();
        for (int t = tid; t < NBUK; t += NTHR) {
            int c = hist[t];
            cbase[t] = (c > 0) ? atomicAdd(&p.slab_cursor[t], c) : 0;
        }
        __syncthreads();
        for (int t = tid; t < NBUK; t += NTHR) hist[t] = 0;
        __syncthreads();
        for (int e = eBeg + tid; e < eEnd; e += NTHR) {
            int d = p.dst[e];
            int b = d >> BSHIFT;
            int r = atomicAdd(&hist[b], 1);
            int pos = cbase[b] + r;
            if (pos < BCAP)
                p.slab[(size_t)b * BCAP + pos] = ((unsigned)p.src[e] << BSHIFT) | (unsigned)(d & 127);
        }
    }
    gsync(p.bar, slot++);

    // ---- P2: scan bucket counts (block 0 only) ----
    if (bid == 0) {
        int* sm = (int*)smem;   // 1024
        int i1 = tid + NTHR;
        int c0 = (tid < NBUK) ? min(p.slab_cursor[tid], BCAP) : 0;
        int c1 = (i1 < NBUK) ? min(p.slab_cursor[i1], BCAP) : 0;
        sm[tid] = c0; sm[i1] = c1;
        __syncthreads();
        for (int off = 1; off < 1024; off <<= 1) {
            int a0 = (tid >= off) ? sm[tid - off] : 0;
            int a1 = (i1 >= off) ? sm[i1 - off] : 0;
            __syncthreads();
            sm[tid] += a0; sm[i1] += a1;
            __syncthreads();
        }
        if (tid < NBUK) p.bucket_base[tid] = sm[tid] - c0;
        if (i1 < NBUK) p.bucket_base[i1] = sm[i1] - c1;
        if (tid == 0) p.row_ptr[NN] = sm[NBUK - 1];
    }
    gsync(p.bar, slot++);

    // ---- P3: per-bucket CSR build + fused layer 1 ----
    {
        SmemBK* s = (SmemBK*)smem;
        if (tid < 256) { s->swl[tid] = p.w1l[tid]; s->swr[tid] = p.w1r[tid]; }
        if (tid < 64)  { s->sb1[tid] = p.b1[tid]; s->ssum[tid] = 0.f; s->ssq[tid] = 0.f; }
        for (int b = bid; b < NBUK; b += GRID_MB) {
            int lo = b << BSHIFT;
            int cnt = min(p.slab_cursor[b], BCAP);
            const unsigned int* sl = p.slab + (size_t)b * BCAP;
            if (tid < 128) s->sdeg[tid] = 0;
            __syncthreads();
            for (int k = tid; k < cnt; k += NTHR)
                atomicAdd(&s->sdeg[sl[k] & 127], 1);
            __syncthreads();
            int v = (tid < 128) ? s->sdeg[tid] : 0;
            if (tid < 128) s->sscan[tid] = v;
            __syncthreads();
            for (int off = 1; off < 128; off <<= 1) {
                int add = 0;
                if (tid < 128 && tid >= off) add = s->sscan[tid - off];
                __syncthreads();
                if (tid < 128) s->sscan[tid] += add;
                __syncthreads();
            }
            int base = p.bucket_base[b];
            if (tid < 128) {
                int excl = s->sscan[tid] - v;
                int n = lo + tid;
                if (n < NN) {
                    p.row_ptr[n] = base + excl;
                    p.deg_inv[n] = 1.0f / fmaxf((float)v, 1.0f);
                }
                s->slcur[tid] = excl;
            }
            __syncthreads();
            for (int k = tid; k < cnt; k += NTHR) {
                unsigned int pk = sl[k];
                int pos = atomicAdd(&s->slcur[pk & 127], 1);
                s->lds_csr[pos] = (int)(pk >> BSHIFT);
            }
            __syncthreads();
            for (int k = tid; k < cnt; k += NTHR) p.csr_src[base + k] = s->lds_csr[k];

            // fused layer 1
            int i = tid >> 2, c = tid & 3;
            int n = lo + i;
            bool valid = (n < NN);
            int dhi = s->sscan[i];
            int dlo2 = dhi - s->sdeg[i];
            const float4* x4 = (const float4*)p.x;
            float4 acc = make_float4(0.f, 0.f, 0.f, 0.f);
            for (int k = dlo2 + c; k < dhi; k += 4) {
                int sx = s->lds_csr[k];
                float4 xv = x4[sx];
                acc.x += xv.x; acc.y += xv.y; acc.z += xv.z; acc.w += xv.w;
            }
#pragma unroll
            for (int m = 1; m <= 2; m <<= 1) {
                acc.x += __shfl_xor(acc.x, m);
                acc.y += __shfl_xor(acc.y, m);
                acc.z += __shfl_xor(acc.z, m);
                acc.w += __shfl_xor(acc.w, m);
            }
            float dv = 1.0f / fmaxf((float)s->sdeg[i], 1.0f);
            float ax = acc.x * dv, ay = acc.y * dv, az = acc.z * dv, aw = acc.w * dv;
            float4 xs = valid ? x4[n] : make_float4(0.f, 0.f, 0.f, 0.f);
#pragma unroll
            for (int m4 = 0; m4 < 4; m4++) {
                float4 o = make_float4(0.f, 0.f, 0.f, 0.f);
                float* op = &o.x;
                if (valid) {
#pragma unroll
                    for (int t = 0; t < 4; t++) {
                        int j = c * 16 + m4 * 4 + t;
                        float sv = s->sb1[j];
                        sv += ax * s->swl[j * 4 + 0] + ay * s->swl[j * 4 + 1] + az * s->swl[j * 4 + 2] + aw * s->swl[j * 4 + 3];
                        sv += xs.x * s->swr[j * 4 + 0] + xs.y * s->swr[j * 4 + 1] + xs.z * s->swr[j * 4 + 2] + xs.w * s->swr[j * 4 + 3];
                        op[t] = sv;
                    }
                    ((float4*)p.hB)[(size_t)n * 16 + c * 4 + m4] = o;
                }
                float4 q = make_float4(o.x * o.x, o.y * o.y, o.z * o.z, o.w * o.w);
#pragma unroll
                for (int m = 4; m <= 32; m <<= 1) {
                    o.x += __shfl_xor(o.x, m); o.y += __shfl_xor(o.y, m);
                    o.z += __shfl_xor(o.z, m); o.w += __shfl_xor(o.w, m);
                    q.x += __shfl_xor(q.x, m); q.y += __shfl_xor(q.y, m);
                    q.z += __shfl_xor(q.z, m); q.w += __shfl_xor(q.w, m);
                }
                if ((tid & 63) < 4) {
                    int jb = c * 16 + m4 * 4;
                    atomicAdd(&s->ssum[jb + 0], o.x); atomicAdd(&s->ssum[jb + 1], o.y);
                    atomicAdd(&s->ssum[jb + 2], o.z); atomicAdd(&s->ssum[jb + 3], o.w);
                    atomicAdd(&s->ssq[jb + 0], q.x);  atomicAdd(&s->ssq[jb + 1], q.y);
                    atomicAdd(&s->ssq[jb + 2], q.z);  atomicAdd(&s->ssq[jb + 3], q.w);
                }
            }
            __syncthreads();
        }
        __syncthreads();
        if (tid < 64) {
            p.part[(2 * tid) * PBMAX + bid]     = s->ssum[tid];
            p.part[(2 * tid + 1) * PBMAX + bid] = s->ssq[tid];
        }
    }
    gsync(p.bar, slot++);

    // ---- BN1 ----
    reduce_sb_phase(p, smem, p.bn1g, p.bn1b);
    gsync(p.bar, slot++);
    bnrelu_phase(p, smem);
    gsync(p.bar, slot++);

    // ---- layer 2 ----
    sage_phase(p, smem, p.w2l, p.b2, p.w2r);
    gsync(p.bar, slot++);
    reduce_sb_phase(p, smem, p.bn2g, p.bn2b);
    gsync(p.bar, slot++);
    bnrelu_phase(p, smem);
    gsync(p.bar, slot++);

    // ---- layer 3 (BN3 applied in pool phase) ----
    sage_phase(p, smem, p.w3l, p.b3, p.w3r);
    gsync(p.bar, slot++);
    reduce_sb_phase(p, smem, p.bn3g, p.bn3b);
    gsync(p.bar, slot++);

    // ---- fused BN3+ReLU+pool+head (blocks 0..127) ----
    if (bid < NG) {
        float* ssc = (float*)smem;
        float* sbi = ssc + 64;
        float* smR = sbi + 64;    // 512
        float* pl  = smR + NTHR;  // 64
        float* hid = pl + 64;     // 64
        if (tid < 64) { ssc[tid] = p.sbv[tid]; sbi[tid] = p.sbv[64 + tid]; }
        __syncthreads();
        int gph = bid;
        int lo = 0, hi = NN;
        while (lo < hi) { int mid = (lo + hi) >> 1; if (p.batch[mid] < gph) lo = mid + 1; else hi = mid; }
        int start = lo;
        hi = NN;
        while (lo < hi) { int mid = (lo + hi) >> 1; if (p.batch[mid] < gph + 1) lo = mid + 1; else hi = mid; }
        int end = lo;

        int c = tid & 63, w = tid >> 6;   // 8 row-walkers
        float sacc = 0.f;
        for (int r = start + w; r < end; r += 8) {
            float v = p.hB[(size_t)r * 64 + c];
            sacc += fmaxf(v * ssc[c] + sbi[c], 0.f);
        }
        smR[tid] = sacc;
        __syncthreads();
        if (tid < 64) {
            float t2 = 0.f;
#pragma unroll
            for (int k = 0; k < 8; k++) t2 += smR[k * 64 + c];
            pl[c] = t2 / fmaxf((float)(end - start), 1.0f);
        }
        __syncthreads();
        if (tid < 64) {
            int j = tid;
            float v = p.fc1b[j];
            for (int k = 0; k < 64; k++) v += pl[k] * p.fc1w[j * 64 + k];
            hid[j] = fmaxf(v, 0.f);
        }
        __syncthreads();
        if (tid < 2) {
            int j = tid;
            float o = p.fc2b[j];
            for (int k = 0; k < 64; k++) o += hid[k] * p.fc2w[j * 64 + k];
            p.out[gph * 2 + j] = o;
        }
    }
}

extern "C" void kernel_launch(void* const* d_in, const int* in_sizes, int n_in,
                              void* d_out, int out_size, void* d_ws, size_t ws_size,
                              hipStream_t stream) {
    Params prm;
    prm.x    = (const float*)d_in[0];
    const int* ei = (const int*)d_in[1];
    prm.src  = ei;
    prm.dst  = ei + NE;
    prm.batch = (const int*)d_in[2];
    prm.w1l = (const float*)d_in[3];  prm.b1 = (const float*)d_in[4];  prm.w1r = (const float*)d_in[5];
    prm.bn1g = (const float*)d_in[6]; prm.bn1b = (const float*)d_in[7];
    prm.w2l = (const float*)d_in[8];  prm.b2 = (const float*)d_in[9];  prm.w2r = (const float*)d_in[10];
    prm.bn2g = (const float*)d_in[11]; prm.bn2b = (const float*)d_in[12];
    prm.w3l = (const float*)d_in[13]; prm.b3 = (const float*)d_in[14]; prm.w3r = (const float*)d_in[15];
    prm.bn3g = (const float*)d_in[16]; prm.bn3b = (const float*)d_in[17];
    prm.fc1w = (const float*)d_in[18]; prm.fc1b = (const float*)d_in[19];
    prm.fc2w = (const float*)d_in[20]; prm.fc2b = (const float*)d_in[21];
    prm.out = (float*)d_out;

    char* ws = (char*)d_ws;
    size_t off = 0;
    auto alloc = [&](size_t bytes) -> char* {
        char* pp = ws + off;
        off += (bytes + 255) & ~(size_t)255;
        return pp;
    };
    prm.csr_src     = (int*)alloc(sizeof(int) * NE);
    prm.hB          = (float*)alloc(sizeof(float) * NN * 64);
    prm.hH          = (__half*)alloc(sizeof(__half) * NN * 64);
    prm.slab        = (unsigned int*)alloc(sizeof(unsigned int) * (size_t)NBUK * BCAP);
    prm.slab_cursor = (int*)alloc(sizeof(int) * NBUK);
    prm.bucket_base = (int*)alloc(sizeof(int) * NBUK);
    prm.row_ptr     = (int*)alloc(sizeof(int) * (NN + 1));
    prm.deg_inv     = (float*)alloc(sizeof(float) * NN);
    prm.part        = (float*)alloc(sizeof(float) * 128 * PBMAX);
    prm.sbv         = (float*)alloc(sizeof(float) * 128);
    prm.bar         = (int*)alloc(sizeof(int) * 64);

    hipMemsetAsync(prm.bar, 0, sizeof(int) * 64, stream);
    k_mega<<<GRID_MB, NTHR, 0, stream>>>(prm);
}